// Round 8
// baseline (779.920 us; speedup 1.0000x reference)
//
#include <hip/hip_runtime.h>
#include <hip/hip_cooperative_groups.h>

namespace cg = cooperative_groups;

#define D 64
#define SLOPE 0.2f
#define BN_EPS 1e-5f
#define BSHIFT 9                  // 512 nodes per bucket
#define BUCKET 512
#define CHUNK 8192                // edges per partition block

// bf16 pack/unpack (RNE)
static __device__ __forceinline__ unsigned pk_bf16(float fx, float fy) {
    unsigned bx = __float_as_uint(fx);
    unsigned by = __float_as_uint(fy);
    bx = (bx + 0x7fffu + ((bx >> 16) & 1u)) >> 16;
    by = (by + 0x7fffu + ((by >> 16) & 1u)) & 0xffff0000u;
    return bx | by;
}
static __device__ __forceinline__ float bf_lo(unsigned u) { return __uint_as_float(u << 16); }
static __device__ __forceinline__ float bf_hi(unsigned u) { return __uint_as_float(u & 0xffff0000u); }

// ---------------------------------------------------------------------------
// CSR build (unchanged from R7)
__global__ __launch_bounds__(256) void k_hist(const int* __restrict__ dst,
                                              int* __restrict__ bcnt, int E) {
    __shared__ int hist[256];
    hist[threadIdx.x] = 0;
    __syncthreads();
    for (int e = blockIdx.x * 256 + threadIdx.x; e < E; e += gridDim.x * 256)
        atomicAdd(&hist[dst[e] >> BSHIFT], 1);
    __syncthreads();
    const int v = hist[threadIdx.x];
    if (v) atomicAdd(&bcnt[threadIdx.x], v);
}

__global__ __launch_bounds__(256) void k_bscan(const int* __restrict__ bcnt,
                                               int* __restrict__ bbase, int* __restrict__ pcur,
                                               unsigned* __restrict__ ybf, int NB, int E, int N) {
    __shared__ int l[256];
    const int t = threadIdx.x;
    const int v = (t < NB) ? bcnt[t] : 0;
    l[t] = v;
    __syncthreads();
    for (int off = 1; off < 256; off <<= 1) {
        int x = l[t];
        if (t >= off) x += l[t - off];
        __syncthreads();
        l[t] = x;
        __syncthreads();
    }
    const int excl = l[t] - v;
    if (t < NB) { bbase[t] = excl; pcur[t] = excl; }
    if (t == 0) bbase[NB] = E;
    if (t < 32) ybf[(size_t)N * 32 + t] = 0u;     // dummy zero row for padded gathers
}

__global__ __launch_bounds__(256) void k_part(const int* __restrict__ src,
                                              const int* __restrict__ dst,
                                              int* __restrict__ pcur,
                                              unsigned* __restrict__ arena, int E) {
    __shared__ unsigned stage[CHUNK];
    __shared__ unsigned char bktb[CHUNK];
    __shared__ int hist[256], lofs[256], gbase[256];
    const int t = threadIdx.x;
    const int e0 = blockIdx.x * CHUNK;
    const int cn = min(CHUNK, E - e0);

    hist[t] = 0;
    __syncthreads();
    for (int i = t; i < cn; i += 256)
        atomicAdd(&hist[dst[e0 + i] >> BSHIFT], 1);
    __syncthreads();
    const int v = hist[t];
    lofs[t] = v;
    __syncthreads();
    for (int off = 1; off < 256; off <<= 1) {
        int x = lofs[t];
        if (t >= off) x += lofs[t - off];
        __syncthreads();
        lofs[t] = x;
        __syncthreads();
    }
    const int excl = lofs[t] - v;
    __syncthreads();
    lofs[t] = excl;
    if (v > 0) gbase[t] = atomicAdd(&pcur[t], v);
    __syncthreads();
    for (int i = t; i < cn; i += 256) {
        const int dd = dst[e0 + i];
        const int b  = dd >> BSHIFT;
        const int p  = atomicAdd(&lofs[b], 1);
        stage[p] = ((unsigned)(dd & (BUCKET - 1)) << 23) | (unsigned)src[e0 + i];
        bktb[p]  = (unsigned char)b;
    }
    __syncthreads();
    for (int i = t; i < cn; i += 256) {
        const int b = bktb[i];
        const int startb = lofs[b] - hist[b];
        arena[gbase[b] + (i - startb)] = stage[i];
    }
}

__global__ __launch_bounds__(512) void k_build(const unsigned* __restrict__ arena,
                                               const int* __restrict__ bbase,
                                               int* __restrict__ rp, int* __restrict__ pcnt,
                                               int* __restrict__ colbuf, float* __restrict__ dinv,
                                               int N) {
    __shared__ int ncnt[512], sc[512], lcur[512];
    const int t = threadIdx.x;
    const int nbase  = blockIdx.x << BSHIFT;
    const int nlocal = min(BUCKET, N - nbase);
    const int abeg = bbase[blockIdx.x];
    const int aend = bbase[blockIdx.x + 1];
    const int pbase = abeg + 7 * nbase;

    ncnt[t] = 0;
    __syncthreads();
    for (int i = abeg + t; i < aend; i += 512)
        atomicAdd(&ncnt[arena[i] >> 23], 1);
    __syncthreads();
    const int v = ncnt[t];
    const int p = (v + 7) & ~7;
    sc[t] = p;
    __syncthreads();
    for (int off = 1; off < 512; off <<= 1) {
        int x = sc[t];
        if (t >= off) x += sc[t - off];
        __syncthreads();
        sc[t] = x;
        __syncthreads();
    }
    const int excl = sc[t] - p;
    lcur[t] = pbase + excl;
    if (t < nlocal) {
        rp[nbase + t]   = pbase + excl;
        pcnt[nbase + t] = p;
        dinv[nbase + t] = rsqrtf((float)v + 1.0f);
    }
    __syncthreads();
    for (int i = abeg + t; i < aend; i += 512) {
        const unsigned u = arena[i];
        const int pos = atomicAdd(&lcur[u >> 23], 1);
        colbuf[pos] = (int)(u & 0x7FFFFFu);
    }
    if (t < nlocal)
        for (int k = v; k < p; ++k) colbuf[pbase + excl + k] = N;
}

// ---------------------------------------------------------------------------
// Fused layer loop: for l in 0..L-1 { gemm -> grid.sync -> pull+stats -> grid.sync } normalize
__global__ __launch_bounds__(256, 4) void k_layers(
    const float* __restrict__ x0, const float* __restrict__ Ws, const float* __restrict__ bs,
    const float* __restrict__ gammas, const float* __restrict__ betas,
    const int* __restrict__ rp, const int* __restrict__ pcnt, const int* __restrict__ colbuf,
    const float* __restrict__ dinv, unsigned* __restrict__ ybf,
    float* __restrict__ h, float* __restrict__ stats, float* __restrict__ out,
    float invN, int N, int L)
{
    cg::grid_group grid = cg::this_grid();
    __shared__ float scs[D], shs[D], l1[D], l2[D];
    const int tid  = threadIdx.x;
    const int bid  = blockIdx.x;
    const int lane = tid & 63;
    const int wv   = tid >> 6;
    const int t32  = lane & 31;
    const int hw   = lane >> 5;
    const int nwaves = gridDim.x * 4;
    const int gwave  = bid * 4 + wv;

    for (int l = 0; l < L; ++l) {
        // ---- fold previous BN affine ----
        if (tid < D) {
            float sc = 1.f, sh = 0.f;
            if (l > 0) {
                const float* st = stats + (size_t)(l - 1) * 128;
                const float mu  = st[tid] * invN;
                const float var = st[D + tid] * invN - mu * mu;
                sc = gammas[(l - 1) * D + tid] * rsqrtf(var + BN_EPS);
                sh = betas[(l - 1) * D + tid] - mu * sc;
            }
            scs[tid] = sc; shs[tid] = sh;
        }
        __syncthreads();

        // ---- gemm: ybf[row] = pack_bf16(((sc*x+sh) @ W) * dinv) ----
        {
            const float* Wl = Ws + (size_t)l * D * D;
            float Wreg[D];
            float bv = 0.f;
#pragma unroll
            for (int k = 0; k < D; ++k) {
                const float w = Wl[k * D + lane];
                Wreg[k] = scs[k] * w;
                bv = fmaf(shs[k], w, bv);
            }
            const float* xin = (l == 0) ? x0 : h;
            for (int row = __builtin_amdgcn_readfirstlane(gwave); row < N; row += nwaves) {
                const float4* xr = (const float4*)(xin + (size_t)row * D);
                float acc = 0.f;
#pragma unroll
                for (int k4 = 0; k4 < 16; ++k4) {
                    const float4 xv = xr[k4];
                    acc = fmaf(xv.x, Wreg[4 * k4 + 0], acc);
                    acc = fmaf(xv.y, Wreg[4 * k4 + 1], acc);
                    acc = fmaf(xv.z, Wreg[4 * k4 + 2], acc);
                    acc = fmaf(xv.w, Wreg[4 * k4 + 3], acc);
                }
                const float r  = (acc + bv) * dinv[row];
                const float rn = __shfl_down(r, 1, 64);
                if (!(lane & 1))
                    ybf[(size_t)row * 32 + (lane >> 1)] = pk_bf16(r, rn);
            }
        }
        grid.sync();

        // ---- pull: half-wave per node, padded edges ----
        {
            const float b0 = bs[l * D + 2 * t32];
            const float b1 = bs[l * D + 2 * t32 + 1];
            float s1a = 0.f, s1b = 0.f, s2a = 0.f, s2b = 0.f;

            for (int pr = gwave; 2 * pr < N; pr += nwaves) {
                const int n  = 2 * pr + hw;
                const bool vn = n < N;
                const int st = vn ? rp[n]   : 0;
                const int pd = vn ? pcnt[n] : 0;

                float a[8][2];
#pragma unroll
                for (int c = 0; c < 8; ++c) { a[c][0] = 0.f; a[c][1] = 0.f; }
                {
                    const unsigned u = vn ? ybf[(size_t)n * 32 + t32] : 0u;
                    a[0][0] = bf_lo(u); a[0][1] = bf_hi(u);
                }
                for (int w0 = 0; w0 < pd; w0 += 32) {
                    const int wn = min(pd - w0, 32);
                    const int ci = (t32 < wn) ? colbuf[st + w0 + t32] : 0;
                    for (int j0 = 0; j0 < wn; j0 += 8) {
#pragma unroll
                        for (int jj = 0; jj < 8; ++jj) {
                            const int idx = __shfl(ci, hw * 32 + j0 + jj, 64);
                            const unsigned u = ybf[(size_t)idx * 32 + t32];
                            a[jj][0] += bf_lo(u);
                            a[jj][1] += bf_hi(u);
                        }
                    }
                }
                const float v0 = ((a[0][0] + a[1][0]) + (a[2][0] + a[3][0])) +
                                 ((a[4][0] + a[5][0]) + (a[6][0] + a[7][0]));
                const float v1 = ((a[0][1] + a[1][1]) + (a[2][1] + a[3][1])) +
                                 ((a[4][1] + a[5][1]) + (a[6][1] + a[7][1]));
                if (vn) {
                    const float di = dinv[n];
                    float t0 = fmaf(di, v0, b0); t0 = t0 > 0.f ? t0 : SLOPE * t0;
                    float t1 = fmaf(di, v1, b1); t1 = t1 > 0.f ? t1 : SLOPE * t1;
                    *(float2*)&h[(size_t)n * D + 2 * t32] = make_float2(t0, t1);
                    s1a += t0; s2a += t0 * t0;
                    s1b += t1; s2b += t1 * t1;
                }
            }

            if (tid < D) { l1[tid] = 0.f; l2[tid] = 0.f; }
            __syncthreads();
            atomicAdd(&l1[2 * t32],     s1a);
            atomicAdd(&l1[2 * t32 + 1], s1b);
            atomicAdd(&l2[2 * t32],     s2a);
            atomicAdd(&l2[2 * t32 + 1], s2b);
            __syncthreads();
            if (tid < D) {
                float* stl = stats + (size_t)l * 128;
                atomicAdd(&stl[tid],     l1[tid]);
                atomicAdd(&stl[D + tid], l2[tid]);
            }
        }
        grid.sync();
    }

    // ---- normalize ----
    {
        const float* st = stats + (size_t)(L - 1) * 128;
        const int gt = bid * 256 + tid;
        const int c0 = (gt * 4) & 63;
        float sc[4], sh[4];
#pragma unroll
        for (int k = 0; k < 4; ++k) {
            const int c = c0 + k;
            const float mu  = st[c] * invN;
            const float var = st[D + c] * invN - mu * mu;
            sc[k] = gammas[(L - 1) * D + c] * rsqrtf(var + BN_EPS);
            sh[k] = betas[(L - 1) * D + c] - mu * sc[k];
        }
        const int total4 = N * D / 4;
        const float4* h4 = (const float4*)h;
        float4* o4 = (float4*)out;
        for (int i = gt; i < total4; i += gridDim.x * 256) {
            float4 v = h4[i];
            v.x = fmaf(sc[0], v.x, sh[0]);
            v.y = fmaf(sc[1], v.y, sh[1]);
            v.z = fmaf(sc[2], v.z, sh[2]);
            v.w = fmaf(sc[3], v.w, sh[3]);
            o4[i] = v;
        }
    }
}

// ---------------------------------------------------------------------------
// Fallback per-phase kernels (identical logic to R7)
__global__ __launch_bounds__(256) void k_gemm(const float* __restrict__ x,
                                              const float* __restrict__ W,
                                              const float* __restrict__ stats,
                                              const float* __restrict__ gamma,
                                              const float* __restrict__ beta,
                                              const float* __restrict__ dinv,
                                              unsigned* __restrict__ ybf,
                                              float invN, int affine, int N) {
    __shared__ float scs[D], shs[D];
    const int tid = threadIdx.x;
    if (tid < D) {
        float sc = 1.f, sh = 0.f;
        if (affine) {
            const float mu  = stats[tid] * invN;
            const float var = stats[D + tid] * invN - mu * mu;
            sc = gamma[tid] * rsqrtf(var + BN_EPS);
            sh = beta[tid] - mu * sc;
        }
        scs[tid] = sc; shs[tid] = sh;
    }
    __syncthreads();
    const int lane = tid & 63;
    const int wib  = tid >> 6;
    float Wreg[D];
    float bv = 0.f;
#pragma unroll
    for (int k = 0; k < D; ++k) {
        const float w = W[k * D + lane];
        Wreg[k] = scs[k] * w;
        bv = fmaf(shs[k], w, bv);
    }
    const int stride = gridDim.x * 4;
    for (int row = __builtin_amdgcn_readfirstlane(blockIdx.x * 4 + wib); row < N; row += stride) {
        const float4* xr = (const float4*)(x + (size_t)row * D);
        float acc = 0.f;
#pragma unroll
        for (int k4 = 0; k4 < 16; ++k4) {
            const float4 xv = xr[k4];
            acc = fmaf(xv.x, Wreg[4 * k4 + 0], acc);
            acc = fmaf(xv.y, Wreg[4 * k4 + 1], acc);
            acc = fmaf(xv.z, Wreg[4 * k4 + 2], acc);
            acc = fmaf(xv.w, Wreg[4 * k4 + 3], acc);
        }
        const float r  = (acc + bv) * dinv[row];
        const float rn = __shfl_down(r, 1, 64);
        if (!(lane & 1))
            ybf[(size_t)row * 32 + (lane >> 1)] = pk_bf16(r, rn);
    }
}

__global__ __launch_bounds__(256) void k_pull(const int* __restrict__ rp,
                                              const int* __restrict__ pcnt,
                                              const int* __restrict__ colbuf,
                                              const unsigned* __restrict__ ybf,
                                              const float* __restrict__ dinv,
                                              const float* __restrict__ b,
                                              float* __restrict__ h,
                                              float* __restrict__ stats, int N) {
    const int tid  = threadIdx.x;
    const int lane = tid & 63;
    const int t32  = lane & 31;
    const int hw   = lane >> 5;
    const int wv   = tid >> 6;
    const float b0 = b[2 * t32];
    const float b1 = b[2 * t32 + 1];
    float s1a = 0.f, s1b = 0.f, s2a = 0.f, s2b = 0.f;
    const int gw = blockIdx.x * 4 + wv;
    const int gstride = gridDim.x * 4;

    for (int pr = gw; 2 * pr < N; pr += gstride) {
        const int n  = 2 * pr + hw;
        const bool vn = n < N;
        const int st = vn ? rp[n]   : 0;
        const int pd = vn ? pcnt[n] : 0;
        float a[8][2];
#pragma unroll
        for (int c = 0; c < 8; ++c) { a[c][0] = 0.f; a[c][1] = 0.f; }
        {
            const unsigned u = vn ? ybf[(size_t)n * 32 + t32] : 0u;
            a[0][0] = bf_lo(u); a[0][1] = bf_hi(u);
        }
        for (int w0 = 0; w0 < pd; w0 += 32) {
            const int wn = min(pd - w0, 32);
            const int ci = (t32 < wn) ? colbuf[st + w0 + t32] : 0;
            for (int j0 = 0; j0 < wn; j0 += 8) {
#pragma unroll
                for (int jj = 0; jj < 8; ++jj) {
                    const int idx = __shfl(ci, hw * 32 + j0 + jj, 64);
                    const unsigned u = ybf[(size_t)idx * 32 + t32];
                    a[jj][0] += bf_lo(u);
                    a[jj][1] += bf_hi(u);
                }
            }
        }
        const float v0 = ((a[0][0] + a[1][0]) + (a[2][0] + a[3][0])) +
                         ((a[4][0] + a[5][0]) + (a[6][0] + a[7][0]));
        const float v1 = ((a[0][1] + a[1][1]) + (a[2][1] + a[3][1])) +
                         ((a[4][1] + a[5][1]) + (a[6][1] + a[7][1]));
        if (vn) {
            const float di = dinv[n];
            float t0 = fmaf(di, v0, b0); t0 = t0 > 0.f ? t0 : SLOPE * t0;
            float t1 = fmaf(di, v1, b1); t1 = t1 > 0.f ? t1 : SLOPE * t1;
            *(float2*)&h[(size_t)n * D + 2 * t32] = make_float2(t0, t1);
            s1a += t0; s2a += t0 * t0;
            s1b += t1; s2b += t1 * t1;
        }
    }
    __shared__ float l1[64], l2[64];
    if (tid < 64) { l1[tid] = 0.f; l2[tid] = 0.f; }
    __syncthreads();
    atomicAdd(&l1[2 * t32],     s1a);
    atomicAdd(&l1[2 * t32 + 1], s1b);
    atomicAdd(&l2[2 * t32],     s2a);
    atomicAdd(&l2[2 * t32 + 1], s2b);
    __syncthreads();
    if (tid < 64) {
        atomicAdd(&stats[tid],      l1[tid]);
        atomicAdd(&stats[64 + tid], l2[tid]);
    }
}

__global__ __launch_bounds__(256) void k_normalize(const float* __restrict__ h,
                                                   const float* __restrict__ stats,
                                                   const float* __restrict__ gamma,
                                                   const float* __restrict__ beta,
                                                   float* __restrict__ out,
                                                   float invN, int total4) {
    const int gt = blockIdx.x * 256 + threadIdx.x;
    const int c0 = (gt * 4) & 63;
    float sc[4], sh[4];
#pragma unroll
    for (int k = 0; k < 4; ++k) {
        const int c = c0 + k;
        const float mu  = stats[c] * invN;
        const float var = stats[64 + c] * invN - mu * mu;
        sc[k] = gamma[c] * rsqrtf(var + BN_EPS);
        sh[k] = beta[c] - mu * sc[k];
    }
    const float4* h4 = (const float4*)h;
    float4* o4 = (float4*)out;
    for (int i = gt; i < total4; i += gridDim.x * 256) {
        float4 v = h4[i];
        v.x = fmaf(sc[0], v.x, sh[0]);
        v.y = fmaf(sc[1], v.y, sh[1]);
        v.z = fmaf(sc[2], v.z, sh[2]);
        v.w = fmaf(sc[3], v.w, sh[3]);
        o4[i] = v;
    }
}

// ---------------------------------------------------------------------------
extern "C" void kernel_launch(void* const* d_in, const int* in_sizes, int n_in,
                              void* d_out, int out_size, void* d_ws, size_t ws_size,
                              hipStream_t stream) {
    const float* x0     = (const float*)d_in[0];
    const int*   ei     = (const int*)d_in[1];
    const float* Ws     = (const float*)d_in[2];
    const float* bs     = (const float*)d_in[3];
    const float* gammas = (const float*)d_in[4];
    const float* betas  = (const float*)d_in[5];

    const int N = in_sizes[0] / D;
    const int E = in_sizes[1] / 2;
    const int L = in_sizes[2] / (D * D);
    const int NB = (N + BUCKET - 1) >> BSHIFT;
    const int nchunks = (E + CHUNK - 1) / CHUNK;

    const int* srcp = ei;
    const int* dstp = ei + E;

    char* wsb = (char*)d_ws;
    size_t o = 0;
    auto alloc = [&](size_t elems) { size_t r = o; o += (elems + 255) & ~(size_t)255; return r; };
    const size_t o_bcnt  = alloc(256);                      // int, zeroed
    const size_t o_stats = alloc((size_t)L * 128);          // float, zeroed
    const size_t zero_end = o;
    const size_t o_bbase = alloc(257);
    const size_t o_pcur  = alloc(256);
    const size_t o_rp    = alloc((size_t)N);
    const size_t o_pcnt  = alloc((size_t)N);
    const size_t o_dinv  = alloc((size_t)N);
    const size_t o_arena = alloc((size_t)E);
    const size_t o_col   = alloc((size_t)E + 7 * (size_t)N + 64);
    const size_t o_y     = alloc(((size_t)N + 1) * 32);
    const size_t o_h     = alloc((size_t)N * D);

    int*      bcnt  = (int*)(wsb + o_bcnt * 4);
    float*    stats = (float*)(wsb + o_stats * 4);
    int*      bbase = (int*)(wsb + o_bbase * 4);
    int*      pcur  = (int*)(wsb + o_pcur * 4);
    int*      rp    = (int*)(wsb + o_rp * 4);
    int*      pcnt  = (int*)(wsb + o_pcnt * 4);
    float*    dinv  = (float*)(wsb + o_dinv * 4);
    unsigned* arena = (unsigned*)(wsb + o_arena * 4);
    int*      col   = (int*)(wsb + o_col * 4);
    unsigned* ybf   = (unsigned*)(wsb + o_y * 4);
    float*    h     = (float*)(wsb + o_h * 4);
    float*    out   = (float*)d_out;

    hipMemsetAsync(d_ws, 0, zero_end * 4, stream);

    k_hist <<<512, 256, 0, stream>>>(dstp, bcnt, E);
    k_bscan<<<1,   256, 0, stream>>>(bcnt, bbase, pcur, ybf, NB, E, N);
    k_part <<<nchunks, 256, 0, stream>>>(srcp, dstp, pcur, arena, E);
    k_build<<<NB,  512, 0, stream>>>(arena, bbase, rp, pcnt, col, dinv, N);

    const float invN = 1.0f / (float)N;

    // ---- try fused cooperative layer loop; fall back to multi-kernel on ANY failure ----
    int dev = 0, nCU = 0, maxB = 0;
    bool coop = (hipGetDevice(&dev) == hipSuccess)
             && (hipDeviceGetAttribute(&nCU, hipDeviceAttributeMultiprocessorCount, dev) == hipSuccess)
             && (hipOccupancyMaxActiveBlocksPerMultiprocessor(&maxB, (const void*)k_layers, 256, 0) == hipSuccess)
             && nCU > 0 && maxB > 0;
    if (coop) {
        int gridsz = nCU * maxB;
        float invN_a = invN;
        int N_a = N, L_a = L;
        void* args[] = {
            (void*)&x0, (void*)&Ws, (void*)&bs, (void*)&gammas, (void*)&betas,
            (void*)&rp, (void*)&pcnt, (void*)&col, (void*)&dinv, (void*)&ybf,
            (void*)&h, (void*)&stats, (void*)&out,
            (void*)&invN_a, (void*)&N_a, (void*)&L_a
        };
        coop = hipLaunchCooperativeKernel((void*)k_layers, dim3(gridsz), dim3(256),
                                          args, 0, stream) == hipSuccess;
    }
    if (!coop) {
        (void)hipGetLastError();   // clear any launch error
        const float* xin = x0;
        for (int l = 0; l < L; ++l) {
            const int pl = l ? l - 1 : 0;
            k_gemm<<<1024, 256, 0, stream>>>(xin, Ws + (size_t)l * D * D,
                                             stats + (size_t)pl * 128,
                                             gammas + (size_t)pl * D, betas + (size_t)pl * D,
                                             dinv, ybf, invN, l > 0 ? 1 : 0, N);
            k_pull<<<2048, 256, 0, stream>>>(rp, pcnt, col, ybf, dinv, bs + (size_t)l * D,
                                             h, stats + (size_t)l * 128, N);
            xin = h;
        }
        k_normalize<<<1024, 256, 0, stream>>>(h, stats + (size_t)(L - 1) * 128,
                                              gammas + (size_t)(L - 1) * D,
                                              betas + (size_t)(L - 1) * D,
                                              out, invN, N * D / 4);
    }
}

// Round 9
// 425.620 us; speedup vs baseline: 1.8324x; 1.8324x over previous
//
#include <hip/hip_runtime.h>

#define D 64
#define SLOPE 0.2f
#define BN_EPS 1e-5f
#define BSHIFT 9                  // 512 nodes per bucket
#define BUCKET 512
#define CHUNK 8192                // edges per partition block

// bf16 pack/unpack (RNE)
static __device__ __forceinline__ unsigned pk_bf16(float fx, float fy) {
    unsigned bx = __float_as_uint(fx);
    unsigned by = __float_as_uint(fy);
    bx = (bx + 0x7fffu + ((bx >> 16) & 1u)) >> 16;
    by = (by + 0x7fffu + ((by >> 16) & 1u)) & 0xffff0000u;
    return bx | by;
}
static __device__ __forceinline__ float bf_lo(unsigned u) { return __uint_as_float(u << 16); }
static __device__ __forceinline__ float bf_hi(unsigned u) { return __uint_as_float(u & 0xffff0000u); }

// ---------------------------------------------------------------------------
// bucket histogram (LDS-aggregated); block 0 also zeroes the dummy ybf row N
__global__ __launch_bounds__(256) void k_hist(const int* __restrict__ dst,
                                              int* __restrict__ bcnt,
                                              unsigned* __restrict__ ybf, int E, int N) {
    __shared__ int hist[256];
    hist[threadIdx.x] = 0;
    __syncthreads();
    if (blockIdx.x == 0 && threadIdx.x < 32) ybf[(size_t)N * 32 + threadIdx.x] = 0u;
    for (int e = blockIdx.x * 256 + threadIdx.x; e < E; e += gridDim.x * 256)
        atomicAdd(&hist[dst[e] >> BSHIFT], 1);
    __syncthreads();
    const int v = hist[threadIdx.x];
    if (v) atomicAdd(&bcnt[threadIdx.x], v);
}

// LDS radix-partition; computes the bucket scan locally from bcnt (no bscan kernel)
__global__ __launch_bounds__(256) void k_part(const int* __restrict__ src,
                                              const int* __restrict__ dst,
                                              const int* __restrict__ bcnt,
                                              int* __restrict__ pcur,
                                              unsigned* __restrict__ arena, int E) {
    __shared__ unsigned stage[CHUNK];
    __shared__ unsigned char bktb[CHUNK];
    __shared__ int bscan[256], hist[256], lofs[256], gbase[256];
    const int t = threadIdx.x;
    const int e0 = blockIdx.x * CHUNK;
    const int cn = min(CHUNK, E - e0);

    // local exclusive scan of global bucket counts
    const int bv = bcnt[t];
    bscan[t] = bv;
    __syncthreads();
    for (int off = 1; off < 256; off <<= 1) {
        int x = bscan[t];
        if (t >= off) x += bscan[t - off];
        __syncthreads();
        bscan[t] = x;
        __syncthreads();
    }
    const int bexcl = bscan[t] - bv;
    __syncthreads();
    bscan[t] = bexcl;
    hist[t] = 0;
    __syncthreads();

    for (int i = t; i < cn; i += 256)
        atomicAdd(&hist[dst[e0 + i] >> BSHIFT], 1);
    __syncthreads();
    const int v = hist[t];
    lofs[t] = v;
    __syncthreads();
    for (int off = 1; off < 256; off <<= 1) {
        int x = lofs[t];
        if (t >= off) x += lofs[t - off];
        __syncthreads();
        lofs[t] = x;
        __syncthreads();
    }
    const int excl = lofs[t] - v;
    __syncthreads();
    lofs[t] = excl;
    if (v > 0) gbase[t] = bscan[t] + atomicAdd(&pcur[t], v);
    __syncthreads();
    for (int i = t; i < cn; i += 256) {
        const int dd = dst[e0 + i];
        const int b  = dd >> BSHIFT;
        const int p  = atomicAdd(&lofs[b], 1);
        stage[p] = ((unsigned)(dd & (BUCKET - 1)) << 23) | (unsigned)src[e0 + i];
        bktb[p]  = (unsigned char)b;
    }
    __syncthreads();
    for (int i = t; i < cn; i += 256) {
        const int b = bktb[i];
        const int startb = lofs[b] - hist[b];
        arena[gbase[b] + (i - startb)] = stage[i];
    }
}

// per-bucket CSR build, 16-padded ranges; local bucket scan from bcnt
__global__ __launch_bounds__(512) void k_build(const unsigned* __restrict__ arena,
                                               const int* __restrict__ bcnt,
                                               int* __restrict__ rp, int* __restrict__ pcnt,
                                               int* __restrict__ colbuf, float* __restrict__ dinv,
                                               int N, int E) {
    __shared__ int bscan[257], ncnt[512], sc[512], lcur[512];
    const int t = threadIdx.x;
    // scan bucket counts (256 values, 512 threads)
    if (t < 256) { bscan[t] = bcnt[t]; }
    __syncthreads();
    if (t < 256) {
        for (int off = 1; off < 256; off <<= 1) {
            int x = bscan[t];
            if (t >= off) x += bscan[t - off];
            __syncthreads();
            bscan[t] = x;
            __syncthreads();
        }
    } else {
        for (int off = 1; off < 256; off <<= 1) { __syncthreads(); __syncthreads(); }
    }
    if (t == 0) bscan[256] = 0;   // unused
    __syncthreads();

    const int b = blockIdx.x;
    const int nbase  = b << BSHIFT;
    const int nlocal = min(BUCKET, N - nbase);
    const int abeg = (b == 0) ? 0 : bscan[b - 1];
    const int aend = bscan[b];
    const int pbase = (abeg + 15 * nbase + 15) & ~15;     // 16-aligned, disjoint per bucket

    ncnt[t] = 0;
    __syncthreads();
    for (int i = abeg + t; i < aend; i += 512)
        atomicAdd(&ncnt[arena[i] >> 23], 1);
    __syncthreads();
    const int v = ncnt[t];
    const int p = (v + 15) & ~15;                          // pad to multiple of 16
    sc[t] = p;
    __syncthreads();
    for (int off = 1; off < 512; off <<= 1) {
        int x = sc[t];
        if (t >= off) x += sc[t - off];
        __syncthreads();
        sc[t] = x;
        __syncthreads();
    }
    const int excl = sc[t] - p;
    lcur[t] = pbase + excl;
    if (t < nlocal) {
        rp[nbase + t]   = pbase + excl;
        pcnt[nbase + t] = p;
        dinv[nbase + t] = rsqrtf((float)v + 1.0f);
    }
    __syncthreads();
    for (int i = abeg + t; i < aend; i += 512) {
        const unsigned u = arena[i];
        const int pos = atomicAdd(&lcur[u >> 23], 1);
        colbuf[pos] = (int)(u & 0x7FFFFFu);
    }
    if (t < nlocal)
        for (int k = v; k < p; ++k) colbuf[pbase + excl + k] = N;   // dummy edges -> zero row
}

// ---------------------------------------------------------------------------
// gemm with folded BN affine: ybf[row] = pack_bf16(((sc*x+sh) @ W) * dinv[row])
__global__ __launch_bounds__(256) void k_gemm(const float* __restrict__ x,
                                              const float* __restrict__ W,
                                              const float* __restrict__ stats,
                                              const float* __restrict__ gamma,
                                              const float* __restrict__ beta,
                                              const float* __restrict__ dinv,
                                              unsigned* __restrict__ ybf,
                                              float invN, int affine, int N) {
    __shared__ float scs[D], shs[D];
    const int tid = threadIdx.x;
    if (tid < D) {
        float sc = 1.f, sh = 0.f;
        if (affine) {
            const float mu  = stats[tid] * invN;
            const float var = stats[D + tid] * invN - mu * mu;
            sc = gamma[tid] * rsqrtf(var + BN_EPS);
            sh = beta[tid] - mu * sc;
        }
        scs[tid] = sc; shs[tid] = sh;
    }
    __syncthreads();
    const int lane = tid & 63;
    const int wib  = tid >> 6;
    float Wreg[D];
    float bv = 0.f;
#pragma unroll
    for (int k = 0; k < D; ++k) {
        const float w = W[k * D + lane];
        Wreg[k] = scs[k] * w;
        bv = fmaf(shs[k], w, bv);
    }
    const int stride = gridDim.x * 4;
    for (int row = __builtin_amdgcn_readfirstlane(blockIdx.x * 4 + wib); row < N; row += stride) {
        const float4* xr = (const float4*)(x + (size_t)row * D);
        float acc = 0.f;
#pragma unroll
        for (int k4 = 0; k4 < 16; ++k4) {
            const float4 xv = xr[k4];
            acc = fmaf(xv.x, Wreg[4 * k4 + 0], acc);
            acc = fmaf(xv.y, Wreg[4 * k4 + 1], acc);
            acc = fmaf(xv.z, Wreg[4 * k4 + 2], acc);
            acc = fmaf(xv.w, Wreg[4 * k4 + 3], acc);
        }
        const float r  = (acc + bv) * dinv[row];
        const float rn = __shfl_down(r, 1, 64);
        if (!(lane & 1))
            ybf[(size_t)row * 32 + (lane >> 1)] = pk_bf16(r, rn);
    }
}

// ---------------------------------------------------------------------------
// pull v3: one wave per node PAIR (both wave-uniform). uint2 gathers: one inst
// covers 4 edges (16 lanes each). Scalarized colbuf indices (uniform int4 loads),
// zero bpermutes in the address path. 16-padded degree -> branch-free inner body.
__global__ __launch_bounds__(256) void k_pull(const int* __restrict__ rp,
                                              const int* __restrict__ pcnt,
                                              const int* __restrict__ colbuf,
                                              const uint2* __restrict__ ybf2,
                                              const float* __restrict__ dinv,
                                              const float* __restrict__ b,
                                              float* __restrict__ h,
                                              float* __restrict__ stats, int N) {
    const int tid  = threadIdx.x;
    const int lane = tid & 63;
    const int sl   = lane & 15;           // slot within row (uint2 = 4 features)
    const int e4   = lane >> 4;           // edge-in-group 0..3
    const int wv   = tid >> 6;
    float bb[4];
#pragma unroll
    for (int f = 0; f < 4; ++f) bb[f] = b[4 * sl + f];
    float s1k[4] = {0.f, 0.f, 0.f, 0.f}, s2k[4] = {0.f, 0.f, 0.f, 0.f};

    const int gw = blockIdx.x * 4 + wv;
    const int gstride = gridDim.x * 4;

    for (int pr = gw; 2 * pr < N; pr += gstride) {
        const int pru = __builtin_amdgcn_readfirstlane(pr);
        const int nA = 2 * pru;
        const int nB = nA + 1;
        const bool hasB = nB < N;
        const int stA = __builtin_amdgcn_readfirstlane(rp[nA]);
        const int pdA = __builtin_amdgcn_readfirstlane(pcnt[nA]);
        int stB = 0, pdB = 0;
        if (hasB) {
            stB = __builtin_amdgcn_readfirstlane(rp[nB]);
            pdB = __builtin_amdgcn_readfirstlane(pcnt[nB]);
        }

        float accA[4][4], accB[4][4];
#pragma unroll
        for (int c = 0; c < 4; ++c)
#pragma unroll
            for (int f = 0; f < 4; ++f) { accA[c][f] = 0.f; accB[c][f] = 0.f; }

        for (int g = 0; g < pdA; g += 16) {
#pragma unroll
            for (int c = 0; c < 4; ++c) {
                const int4 ip = *(const int4*)&colbuf[stA + g + 4 * c];
                int id = ip.x;
                id = (e4 == 1) ? ip.y : id;
                id = (e4 == 2) ? ip.z : id;
                id = (e4 == 3) ? ip.w : id;
                const uint2 u = ybf2[(size_t)id * 16 + sl];
                accA[c][0] += bf_lo(u.x); accA[c][1] += bf_hi(u.x);
                accA[c][2] += bf_lo(u.y); accA[c][3] += bf_hi(u.y);
            }
        }
        for (int g = 0; g < pdB; g += 16) {
#pragma unroll
            for (int c = 0; c < 4; ++c) {
                const int4 ip = *(const int4*)&colbuf[stB + g + 4 * c];
                int id = ip.x;
                id = (e4 == 1) ? ip.y : id;
                id = (e4 == 2) ? ip.z : id;
                id = (e4 == 3) ? ip.w : id;
                const uint2 u = ybf2[(size_t)id * 16 + sl];
                accB[c][0] += bf_lo(u.x); accB[c][1] += bf_hi(u.x);
                accB[c][2] += bf_lo(u.y); accB[c][3] += bf_hi(u.y);
            }
        }

        float vA[4], vB[4];
#pragma unroll
        for (int f = 0; f < 4; ++f) {
            vA[f] = (accA[0][f] + accA[1][f]) + (accA[2][f] + accA[3][f]);
            vA[f] += __shfl_xor(vA[f], 16, 64);
            vA[f] += __shfl_xor(vA[f], 32, 64);
            vB[f] = (accB[0][f] + accB[1][f]) + (accB[2][f] + accB[3][f]);
            vB[f] += __shfl_xor(vB[f], 16, 64);
            vB[f] += __shfl_xor(vB[f], 32, 64);
        }

        if (lane < 16) {
            {   // node A
                const uint2 su = ybf2[(size_t)nA * 16 + sl];
                const float self[4] = {bf_lo(su.x), bf_hi(su.x), bf_lo(su.y), bf_hi(su.y)};
                const float di = dinv[nA];
                float4 hv; float* hp = &hv.x;
#pragma unroll
                for (int f = 0; f < 4; ++f) {
                    float t = fmaf(di, vA[f] + self[f], bb[f]);
                    t = t > 0.f ? t : SLOPE * t;
                    hp[f] = t; s1k[f] += t; s2k[f] += t * t;
                }
                *(float4*)&h[(size_t)nA * D + 4 * sl] = hv;
            }
            if (hasB) {   // node B
                const uint2 su = ybf2[(size_t)nB * 16 + sl];
                const float self[4] = {bf_lo(su.x), bf_hi(su.x), bf_lo(su.y), bf_hi(su.y)};
                const float di = dinv[nB];
                float4 hv; float* hp = &hv.x;
#pragma unroll
                for (int f = 0; f < 4; ++f) {
                    float t = fmaf(di, vB[f] + self[f], bb[f]);
                    t = t > 0.f ? t : SLOPE * t;
                    hp[f] = t; s1k[f] += t; s2k[f] += t * t;
                }
                *(float4*)&h[(size_t)nB * D + 4 * sl] = hv;
            }
        }
    }

    __shared__ float ls1[64], ls2[64];
    if (tid < 64) { ls1[tid] = 0.f; ls2[tid] = 0.f; }
    __syncthreads();
    if (lane < 16) {
#pragma unroll
        for (int f = 0; f < 4; ++f) {
            atomicAdd(&ls1[4 * sl + f], s1k[f]);
            atomicAdd(&ls2[4 * sl + f], s2k[f]);
        }
    }
    __syncthreads();
    if (tid < 64) {
        atomicAdd(&stats[tid],      ls1[tid]);
        atomicAdd(&stats[64 + tid], ls2[tid]);
    }
}

// ---------------------------------------------------------------------------
__global__ __launch_bounds__(256) void k_normalize(const float* __restrict__ h,
                                                   const float* __restrict__ stats,
                                                   const float* __restrict__ gamma,
                                                   const float* __restrict__ beta,
                                                   float* __restrict__ out,
                                                   float invN, int total4) {
    const int gt = blockIdx.x * 256 + threadIdx.x;
    const int c0 = (gt * 4) & 63;
    float sc[4], sh[4];
#pragma unroll
    for (int k = 0; k < 4; ++k) {
        const int c = c0 + k;
        const float mu  = stats[c] * invN;
        const float var = stats[64 + c] * invN - mu * mu;
        sc[k] = gamma[c] * rsqrtf(var + BN_EPS);
        sh[k] = beta[c] - mu * sc[k];
    }
    const float4* h4 = (const float4*)h;
    float4* o4 = (float4*)out;
    for (int i = gt; i < total4; i += gridDim.x * 256) {
        float4 v = h4[i];
        v.x = fmaf(sc[0], v.x, sh[0]);
        v.y = fmaf(sc[1], v.y, sh[1]);
        v.z = fmaf(sc[2], v.z, sh[2]);
        v.w = fmaf(sc[3], v.w, sh[3]);
        o4[i] = v;
    }
}

// ---------------------------------------------------------------------------
extern "C" void kernel_launch(void* const* d_in, const int* in_sizes, int n_in,
                              void* d_out, int out_size, void* d_ws, size_t ws_size,
                              hipStream_t stream) {
    const float* x0     = (const float*)d_in[0];
    const int*   ei     = (const int*)d_in[1];
    const float* Ws     = (const float*)d_in[2];
    const float* bs     = (const float*)d_in[3];
    const float* gammas = (const float*)d_in[4];
    const float* betas  = (const float*)d_in[5];

    const int N = in_sizes[0] / D;
    const int E = in_sizes[1] / 2;
    const int L = in_sizes[2] / (D * D);
    const int nchunks = (E + CHUNK - 1) / CHUNK;
    const int NB = (N + BUCKET - 1) >> BSHIFT;

    const int* srcp = ei;
    const int* dstp = ei + E;

    char* wsb = (char*)d_ws;
    size_t o = 0;
    auto alloc = [&](size_t elems) { size_t r = o; o += (elems + 255) & ~(size_t)255; return r; };
    const size_t o_bcnt  = alloc(256);                               // int, zeroed
    const size_t o_pcur  = alloc(256);                               // int, zeroed
    const size_t o_stats = alloc((size_t)L * 128);                   // float, zeroed
    const size_t zero_end = o;
    const size_t o_rp    = alloc((size_t)N);                         // int
    const size_t o_pcnt  = alloc((size_t)N);                         // int
    const size_t o_dinv  = alloc((size_t)N);                         // float
    const size_t o_arena = alloc((size_t)E);                         // uint (packed)
    const size_t o_col   = alloc((size_t)E + 15 * (size_t)N + 16 * 256 + 256); // int, 16-padded
    const size_t o_y     = alloc(((size_t)N + 1) * 32);              // uint (bf16x2), +dummy row
    const size_t o_h     = alloc((size_t)N * D);                     // float

    int*      bcnt  = (int*)(wsb + o_bcnt * 4);
    int*      pcur  = (int*)(wsb + o_pcur * 4);
    float*    stats = (float*)(wsb + o_stats * 4);
    int*      rp    = (int*)(wsb + o_rp * 4);
    int*      pcnt  = (int*)(wsb + o_pcnt * 4);
    float*    dinv  = (float*)(wsb + o_dinv * 4);
    unsigned* arena = (unsigned*)(wsb + o_arena * 4);
    int*      col   = (int*)(wsb + o_col * 4);
    unsigned* ybf   = (unsigned*)(wsb + o_y * 4);
    float*    h     = (float*)(wsb + o_h * 4);
    float*    out   = (float*)d_out;

    hipMemsetAsync(d_ws, 0, zero_end * 4, stream);

    k_hist <<<512, 256, 0, stream>>>(dstp, bcnt, ybf, E, N);
    k_part <<<nchunks, 256, 0, stream>>>(srcp, dstp, bcnt, pcur, arena, E);
    k_build<<<NB, 512, 0, stream>>>(arena, bcnt, rp, pcnt, col, dinv, N, E);

    const float invN = 1.0f / (float)N;
    const float* xin = x0;
    for (int l = 0; l < L; ++l) {
        const int pl = l ? l - 1 : 0;
        k_gemm<<<1024, 256, 0, stream>>>(xin, Ws + (size_t)l * D * D,
                                         stats + (size_t)pl * 128,
                                         gammas + (size_t)pl * D, betas + (size_t)pl * D,
                                         dinv, ybf, invN, l > 0 ? 1 : 0, N);
        k_pull<<<2048, 256, 0, stream>>>(rp, pcnt, col, (const uint2*)ybf, dinv,
                                         bs + (size_t)l * D, h, stats + (size_t)l * 128, N);
        xin = h;
    }
    k_normalize<<<1024, 256, 0, stream>>>(h, stats + (size_t)(L - 1) * 128,
                                          gammas + (size_t)(L - 1) * D,
                                          betas + (size_t)(L - 1) * D,
                                          out, invN, N * D / 4);
}

// Round 10
// 425.600 us; speedup vs baseline: 1.8325x; 1.0000x over previous
//
#include <hip/hip_runtime.h>

#define D 64
#define SLOPE 0.2f
#define BN_EPS 1e-5f
#define BSHIFT 9                  // 512 nodes per bucket
#define BUCKET 512
#define CHUNK 8192                // edges per partition block

// bf16 pack/unpack (RNE)
static __device__ __forceinline__ unsigned pk_bf16(float fx, float fy) {
    unsigned bx = __float_as_uint(fx);
    unsigned by = __float_as_uint(fy);
    bx = (bx + 0x7fffu + ((bx >> 16) & 1u)) >> 16;
    by = (by + 0x7fffu + ((by >> 16) & 1u)) & 0xffff0000u;
    return bx | by;
}
static __device__ __forceinline__ float bf_lo(unsigned u) { return __uint_as_float(u << 16); }
static __device__ __forceinline__ float bf_hi(unsigned u) { return __uint_as_float(u & 0xffff0000u); }

// ---------------------------------------------------------------------------
// bucket histogram (LDS-aggregated); block 0 also zeroes the dummy ybf row N
__global__ __launch_bounds__(256) void k_hist(const int* __restrict__ dst,
                                              int* __restrict__ bcnt,
                                              unsigned* __restrict__ ybf, int E, int N) {
    __shared__ int hist[256];
    hist[threadIdx.x] = 0;
    __syncthreads();
    if (blockIdx.x == 0 && threadIdx.x < 32) ybf[(size_t)N * 32 + threadIdx.x] = 0u;
    for (int e = blockIdx.x * 256 + threadIdx.x; e < E; e += gridDim.x * 256)
        atomicAdd(&hist[dst[e] >> BSHIFT], 1);
    __syncthreads();
    const int v = hist[threadIdx.x];
    if (v) atomicAdd(&bcnt[threadIdx.x], v);
}

// LDS radix-partition; computes the bucket scan locally from bcnt
__global__ __launch_bounds__(256) void k_part(const int* __restrict__ src,
                                              const int* __restrict__ dst,
                                              const int* __restrict__ bcnt,
                                              int* __restrict__ pcur,
                                              unsigned* __restrict__ arena, int E) {
    __shared__ unsigned stage[CHUNK];
    __shared__ unsigned char bktb[CHUNK];
    __shared__ int bscan[256], hist[256], lofs[256], gbase[256];
    const int t = threadIdx.x;
    const int e0 = blockIdx.x * CHUNK;
    const int cn = min(CHUNK, E - e0);

    const int bv = bcnt[t];
    bscan[t] = bv;
    __syncthreads();
    for (int off = 1; off < 256; off <<= 1) {
        int x = bscan[t];
        if (t >= off) x += bscan[t - off];
        __syncthreads();
        bscan[t] = x;
        __syncthreads();
    }
    const int bexcl = bscan[t] - bv;
    __syncthreads();
    bscan[t] = bexcl;
    hist[t] = 0;
    __syncthreads();

    for (int i = t; i < cn; i += 256)
        atomicAdd(&hist[dst[e0 + i] >> BSHIFT], 1);
    __syncthreads();
    const int v = hist[t];
    lofs[t] = v;
    __syncthreads();
    for (int off = 1; off < 256; off <<= 1) {
        int x = lofs[t];
        if (t >= off) x += lofs[t - off];
        __syncthreads();
        lofs[t] = x;
        __syncthreads();
    }
    const int excl = lofs[t] - v;
    __syncthreads();
    lofs[t] = excl;
    if (v > 0) gbase[t] = bscan[t] + atomicAdd(&pcur[t], v);
    __syncthreads();
    for (int i = t; i < cn; i += 256) {
        const int dd = dst[e0 + i];
        const int b  = dd >> BSHIFT;
        const int p  = atomicAdd(&lofs[b], 1);
        stage[p] = ((unsigned)(dd & (BUCKET - 1)) << 23) | (unsigned)src[e0 + i];
        bktb[p]  = (unsigned char)b;
    }
    __syncthreads();
    for (int i = t; i < cn; i += 256) {
        const int b = bktb[i];
        const int startb = lofs[b] - hist[b];
        arena[gbase[b] + (i - startb)] = stage[i];
    }
}

// per-bucket CSR build (8-padded) + in-bucket degree counting-sort -> perm pairs
__global__ __launch_bounds__(512) void k_build(const unsigned* __restrict__ arena,
                                               const int* __restrict__ bcnt,
                                               int* __restrict__ rp, int* __restrict__ pcnt,
                                               int* __restrict__ colbuf, float* __restrict__ dinv,
                                               int* __restrict__ perm, int N) {
    __shared__ int bscan[256], ncnt[512], sc[512], lcur[512];
    const int t = threadIdx.x;
    // bucket-count scan (256 entries, 512 threads: idle half mirrors barriers)
    if (t < 256) bscan[t] = bcnt[t];
    __syncthreads();
    if (t < 256) {
        for (int off = 1; off < 256; off <<= 1) {
            int x = bscan[t];
            if (t >= off) x += bscan[t - off];
            __syncthreads();
            bscan[t] = x;
            __syncthreads();
        }
    } else {
        for (int off = 1; off < 256; off <<= 1) { __syncthreads(); __syncthreads(); }
    }
    __syncthreads();

    const int b = blockIdx.x;
    const int nbase  = b << BSHIFT;
    const int nlocal = min(BUCKET, N - nbase);
    const int abeg = (b == 0) ? 0 : bscan[b - 1];
    const int aend = bscan[b];
    const int pbase = abeg + 7 * nbase;          // 8-pad region base, disjoint per bucket

    ncnt[t] = 0;
    __syncthreads();
    for (int i = abeg + t; i < aend; i += 512)
        atomicAdd(&ncnt[arena[i] >> 23], 1);
    __syncthreads();
    const int v = ncnt[t];
    const int p = (v + 7) & ~7;                  // pad to multiple of 8
    sc[t] = p;
    __syncthreads();
    for (int off = 1; off < 512; off <<= 1) {
        int x = sc[t];
        if (t >= off) x += sc[t - off];
        __syncthreads();
        sc[t] = x;
        __syncthreads();
    }
    const int excl = sc[t] - p;
    lcur[t] = pbase + excl;
    if (t < nlocal) {
        rp[nbase + t]   = pbase + excl;
        pcnt[nbase + t] = p;
        dinv[nbase + t] = rsqrtf((float)v + 1.0f);
    }
    __syncthreads();
    for (int i = abeg + t; i < aend; i += 512) {
        const unsigned u = arena[i];
        const int pos = atomicAdd(&lcur[u >> 23], 1);
        colbuf[pos] = (int)(u & 0x7FFFFFu);
    }
    if (t < nlocal)
        for (int k = v; k < p; ++k) colbuf[pbase + excl + k] = N;   // dummy -> zero row

    // ---- degree counting-sort within bucket -> perm (equal-degree pairs) ----
    __syncthreads();
    const int dkey = v > 511 ? 511 : v;
    ncnt[t] = 0;                                  // reuse as degree histogram
    lcur[t] = 0;                                  // reuse as per-bin cursor
    __syncthreads();
    if (t < nlocal) atomicAdd(&ncnt[dkey], 1);
    __syncthreads();
    sc[t] = ncnt[t];                              // reuse as histogram scan
    __syncthreads();
    for (int off = 1; off < 512; off <<= 1) {
        int x = sc[t];
        if (t >= off) x += sc[t - off];
        __syncthreads();
        sc[t] = x;
        __syncthreads();
    }
    __syncthreads();
    if (t < nlocal) {
        const int binstart = sc[dkey] - ncnt[dkey];
        const int rank = atomicAdd(&lcur[dkey], 1);
        perm[nbase + binstart + rank] = nbase + t;
    } else {
        perm[nbase + t] = -1;                     // sentinel for tail slots
    }
}

// ---------------------------------------------------------------------------
// gemm with folded BN affine: ybf[row] = pack_bf16(((sc*x+sh) @ W) * dinv[row])
__global__ __launch_bounds__(256) void k_gemm(const float* __restrict__ x,
                                              const float* __restrict__ W,
                                              const float* __restrict__ stats,
                                              const float* __restrict__ gamma,
                                              const float* __restrict__ beta,
                                              const float* __restrict__ dinv,
                                              unsigned* __restrict__ ybf,
                                              float invN, int affine, int N) {
    __shared__ float scs[D], shs[D];
    const int tid = threadIdx.x;
    if (tid < D) {
        float sc = 1.f, sh = 0.f;
        if (affine) {
            const float mu  = stats[tid] * invN;
            const float var = stats[D + tid] * invN - mu * mu;
            sc = gamma[tid] * rsqrtf(var + BN_EPS);
            sh = beta[tid] - mu * sc;
        }
        scs[tid] = sc; shs[tid] = sh;
    }
    __syncthreads();
    const int lane = tid & 63;
    const int wib  = tid >> 6;
    float Wreg[D];
    float bv = 0.f;
#pragma unroll
    for (int k = 0; k < D; ++k) {
        const float w = W[k * D + lane];
        Wreg[k] = scs[k] * w;
        bv = fmaf(shs[k], w, bv);
    }
    const int stride = gridDim.x * 4;
    for (int row = __builtin_amdgcn_readfirstlane(blockIdx.x * 4 + wib); row < N; row += stride) {
        const float4* xr = (const float4*)(x + (size_t)row * D);
        float acc = 0.f;
#pragma unroll
        for (int k4 = 0; k4 < 16; ++k4) {
            const float4 xv = xr[k4];
            acc = fmaf(xv.x, Wreg[4 * k4 + 0], acc);
            acc = fmaf(xv.y, Wreg[4 * k4 + 1], acc);
            acc = fmaf(xv.z, Wreg[4 * k4 + 2], acc);
            acc = fmaf(xv.w, Wreg[4 * k4 + 3], acc);
        }
        const float r  = (acc + bv) * dinv[row];
        const float rn = __shfl_down(r, 1, 64);
        if (!(lane & 1))
            ybf[(size_t)row * 32 + (lane >> 1)] = pk_bf16(r, rn);
    }
}

// ---------------------------------------------------------------------------
// pull (R7 structure): half-wave per node, degree-matched pairs via perm,
// 8 independent gather chains, padded edges -> branch-free inner body.
__global__ __launch_bounds__(256) void k_pull(const int* __restrict__ rp,
                                              const int* __restrict__ pcnt,
                                              const int* __restrict__ colbuf,
                                              const unsigned* __restrict__ ybf,
                                              const float* __restrict__ dinv,
                                              const float* __restrict__ b,
                                              const int* __restrict__ perm,
                                              float* __restrict__ h,
                                              float* __restrict__ stats,
                                              int npairs, int N) {
    const int tid  = threadIdx.x;
    const int lane = tid & 63;
    const int t32  = lane & 31;
    const int hw   = lane >> 5;
    const int wv   = tid >> 6;
    const float b0 = b[2 * t32];
    const float b1 = b[2 * t32 + 1];
    float s1a = 0.f, s1b = 0.f, s2a = 0.f, s2b = 0.f;
    const int gw = blockIdx.x * 4 + wv;
    const int gstride = gridDim.x * 4;

    for (int pr = gw; pr < npairs; pr += gstride) {
        const int n  = perm[2 * pr + hw];        // degree-matched partner; -1 sentinel
        const bool vn = n >= 0;
        const int st = vn ? rp[n]   : 0;
        const int pd = vn ? pcnt[n] : 0;

        float a[8][2];
#pragma unroll
        for (int c = 0; c < 8; ++c) { a[c][0] = 0.f; a[c][1] = 0.f; }
        {   // self term
            const unsigned u = vn ? ybf[(size_t)n * 32 + t32] : 0u;
            a[0][0] = bf_lo(u); a[0][1] = bf_hi(u);
        }
        for (int w0 = 0; w0 < pd; w0 += 32) {
            const int wn = min(pd - w0, 32);                 // multiple of 8
            const int ci = (t32 < wn) ? colbuf[st + w0 + t32] : 0;
            for (int j0 = 0; j0 < wn; j0 += 8) {
#pragma unroll
                for (int jj = 0; jj < 8; ++jj) {
                    const int idx = __shfl(ci, hw * 32 + j0 + jj, 64);
                    const unsigned u = ybf[(size_t)idx * 32 + t32];
                    a[jj][0] += bf_lo(u);
                    a[jj][1] += bf_hi(u);
                }
            }
        }
        const float v0 = ((a[0][0] + a[1][0]) + (a[2][0] + a[3][0])) +
                         ((a[4][0] + a[5][0]) + (a[6][0] + a[7][0]));
        const float v1 = ((a[0][1] + a[1][1]) + (a[2][1] + a[3][1])) +
                         ((a[4][1] + a[5][1]) + (a[6][1] + a[7][1]));
        if (vn) {
            const float di = dinv[n];
            float t0 = fmaf(di, v0, b0); t0 = t0 > 0.f ? t0 : SLOPE * t0;
            float t1 = fmaf(di, v1, b1); t1 = t1 > 0.f ? t1 : SLOPE * t1;
            *(float2*)&h[(size_t)n * D + 2 * t32] = make_float2(t0, t1);
            s1a += t0; s2a += t0 * t0;
            s1b += t1; s2b += t1 * t1;
        }
    }

    __shared__ float l1[64], l2[64];
    if (tid < 64) { l1[tid] = 0.f; l2[tid] = 0.f; }
    __syncthreads();
    atomicAdd(&l1[2 * t32],     s1a);
    atomicAdd(&l1[2 * t32 + 1], s1b);
    atomicAdd(&l2[2 * t32],     s2a);
    atomicAdd(&l2[2 * t32 + 1], s2b);
    __syncthreads();
    if (tid < 64) {
        atomicAdd(&stats[tid],      l1[tid]);
        atomicAdd(&stats[64 + tid], l2[tid]);
    }
}

// ---------------------------------------------------------------------------
__global__ __launch_bounds__(256) void k_normalize(const float* __restrict__ h,
                                                   const float* __restrict__ stats,
                                                   const float* __restrict__ gamma,
                                                   const float* __restrict__ beta,
                                                   float* __restrict__ out,
                                                   float invN, int total4) {
    const int gt = blockIdx.x * 256 + threadIdx.x;
    const int c0 = (gt * 4) & 63;
    float sc[4], sh[4];
#pragma unroll
    for (int k = 0; k < 4; ++k) {
        const int c = c0 + k;
        const float mu  = stats[c] * invN;
        const float var = stats[64 + c] * invN - mu * mu;
        sc[k] = gamma[c] * rsqrtf(var + BN_EPS);
        sh[k] = beta[c] - mu * sc[k];
    }
    const float4* h4 = (const float4*)h;
    float4* o4 = (float4*)out;
    for (int i = gt; i < total4; i += gridDim.x * 256) {
        float4 v = h4[i];
        v.x = fmaf(sc[0], v.x, sh[0]);
        v.y = fmaf(sc[1], v.y, sh[1]);
        v.z = fmaf(sc[2], v.z, sh[2]);
        v.w = fmaf(sc[3], v.w, sh[3]);
        o4[i] = v;
    }
}

// ---------------------------------------------------------------------------
extern "C" void kernel_launch(void* const* d_in, const int* in_sizes, int n_in,
                              void* d_out, int out_size, void* d_ws, size_t ws_size,
                              hipStream_t stream) {
    const float* x0     = (const float*)d_in[0];
    const int*   ei     = (const int*)d_in[1];
    const float* Ws     = (const float*)d_in[2];
    const float* bs     = (const float*)d_in[3];
    const float* gammas = (const float*)d_in[4];
    const float* betas  = (const float*)d_in[5];

    const int N = in_sizes[0] / D;
    const int E = in_sizes[1] / 2;
    const int L = in_sizes[2] / (D * D);
    const int nchunks = (E + CHUNK - 1) / CHUNK;
    const int NB = (N + BUCKET - 1) >> BSHIFT;
    const int npairs = NB * (BUCKET / 2);

    const int* srcp = ei;
    const int* dstp = ei + E;

    char* wsb = (char*)d_ws;
    size_t o = 0;
    auto alloc = [&](size_t elems) { size_t r = o; o += (elems + 255) & ~(size_t)255; return r; };
    const size_t o_bcnt  = alloc(256);                               // int, zeroed
    const size_t o_pcur  = alloc(256);                               // int, zeroed
    const size_t o_stats = alloc((size_t)L * 128);                   // float, zeroed
    const size_t zero_end = o;
    const size_t o_rp    = alloc((size_t)N);                         // int
    const size_t o_pcnt  = alloc((size_t)N);                         // int
    const size_t o_dinv  = alloc((size_t)N);                         // float
    const size_t o_perm  = alloc((size_t)NB * BUCKET);               // int
    const size_t o_arena = alloc((size_t)E);                         // uint (packed)
    const size_t o_col   = alloc((size_t)E + 7 * (size_t)N + 512);   // int, 8-padded
    const size_t o_y     = alloc(((size_t)N + 1) * 32);              // uint (bf16x2), +dummy row
    const size_t o_h     = alloc((size_t)N * D);                     // float

    int*      bcnt  = (int*)(wsb + o_bcnt * 4);
    int*      pcur  = (int*)(wsb + o_pcur * 4);
    float*    stats = (float*)(wsb + o_stats * 4);
    int*      rp    = (int*)(wsb + o_rp * 4);
    int*      pcnt  = (int*)(wsb + o_pcnt * 4);
    float*    dinv  = (float*)(wsb + o_dinv * 4);
    int*      perm  = (int*)(wsb + o_perm * 4);
    unsigned* arena = (unsigned*)(wsb + o_arena * 4);
    int*      col   = (int*)(wsb + o_col * 4);
    unsigned* ybf   = (unsigned*)(wsb + o_y * 4);
    float*    h     = (float*)(wsb + o_h * 4);
    float*    out   = (float*)d_out;

    hipMemsetAsync(d_ws, 0, zero_end * 4, stream);

    k_hist <<<512, 256, 0, stream>>>(dstp, bcnt, ybf, E, N);
    k_part <<<nchunks, 256, 0, stream>>>(srcp, dstp, bcnt, pcur, arena, E);
    k_build<<<NB, 512, 0, stream>>>(arena, bcnt, rp, pcnt, col, dinv, perm, N);

    const float invN = 1.0f / (float)N;
    const float* xin = x0;
    for (int l = 0; l < L; ++l) {
        const int pl = l ? l - 1 : 0;
        k_gemm<<<1024, 256, 0, stream>>>(xin, Ws + (size_t)l * D * D,
                                         stats + (size_t)pl * 128,
                                         gammas + (size_t)pl * D, betas + (size_t)pl * D,
                                         dinv, ybf, invN, l > 0 ? 1 : 0, N);
        k_pull<<<2048, 256, 0, stream>>>(rp, pcnt, col, ybf, dinv,
                                         bs + (size_t)l * D, perm, h,
                                         stats + (size_t)l * 128, npairs, N);
        xin = h;
    }
    k_normalize<<<1024, 256, 0, stream>>>(h, stats + (size_t)(L - 1) * 128,
                                          gammas + (size_t)(L - 1) * D,
                                          betas + (size_t)(L - 1) * D,
                                          out, invN, N * D / 4);
}